// Round 4
// baseline (130.342 us; speedup 1.0000x reference)
//
#include <hip/hip_runtime.h>

// Problem constants: B=32, H=W=512
#define BATCH 32
#define HW 262144           // elements per image
#define HW4 65536           // float4 per image
#define W_IMG 512
#define N_BLOCKS 1024       // 32 batches * 32 bands (16 rows each)
#define N_BOX 96            // B * 3

// Workspace layout (doubles) — every slot written unconditionally by its block:
//  [0..1023]     per-block sum of output      (slot = batch*32 + band)
//  [1024..2047]  per-block sum of density
//  [2048..3071]  per-block sum of (o-d)^2
//  [3072..6143]  box partials: slot = box*32 + band  (96 boxes x 32 bands)
//  byte offset 6144*8: uint32 ticket (zeroed via hipMemsetAsync each launch)
#define WS_SO   0
#define WS_SD   1024
#define WS_SQ   2048
#define WS_BOX  3072
#define WS_TICKET_BYTES (6144 * 8)

__device__ __forceinline__ double wave_reduce_d(double v) {
    for (int off = 32; off > 0; off >>= 1)
        v += __shfl_down(v, off, 64);
    return v;
}

// Single kernel: each block streams a 16-row band of one image computing
// sum(o), sum(d), sum((o-d)^2) and partials of its batch's 3 boxes from
// registers; the last block to finish reduces all partials and writes d_out.
__global__ __launch_bounds__(256) void fused_all(const float4* __restrict__ o4,
                                                 const float4* __restrict__ d4,
                                                 const int* __restrict__ bb,
                                                 double* __restrict__ ws,
                                                 const int* __restrict__ nobj,
                                                 float* __restrict__ out) {
    const int blk = blockIdx.x;
    const int batch = blk >> 5;
    const int band = blk & 31;                 // rows [band*16, band*16+16)
    const size_t base = (size_t)blk * 2048;    // float4 index
    const int t = threadIdx.x;
    const int lane = t & 63;
    const int wid = t >> 6;
    const int col0 = (t & 127) * 4;            // constant per thread across iters
    const int rbase = band * 16 + (t >> 7);    // row at iter i = rbase + 2*i

    // Per-box precompute: column masks (constant per thread) + row range.
    float wm[3][4];
    int by1[3], by2[3];
    bool active[3];
#pragma unroll
    for (int k = 0; k < 3; ++k) {
        const int* p = bb + (batch * 3 + k) * 4;
        int x1 = min(max(p[0], 0), W_IMG);
        int y1 = min(max(p[1], 0), W_IMG);
        int x2 = min(max(p[2], 0), W_IMG);
        int y2 = min(max(p[3], 0), W_IMG);
        x2 = max(x2, x1);
        y2 = max(y2, y1);
        by1[k] = y1; by2[k] = y2;
#pragma unroll
        for (int j = 0; j < 4; ++j) {
            int c = col0 + j;
            wm[k][j] = (c >= x1 && c < x2) ? 1.0f : 0.0f;
        }
        active[k] = (y2 > band * 16) && (y1 < band * 16 + 16);  // block-uniform
    }

    double so = 0.0, sd = 0.0, ssq = 0.0;
    float bxs[3] = {0.0f, 0.0f, 0.0f};

#pragma unroll
    for (int i = 0; i < 8; ++i) {
        size_t idx = base + t + i * 256;
        float4 a = o4[idx];
        float4 b = d4[idx];
        so += (double)a.x + (double)a.y + (double)a.z + (double)a.w;
        sd += (double)b.x + (double)b.y + (double)b.z + (double)b.w;
        double dx = (double)a.x - (double)b.x;
        double dy = (double)a.y - (double)b.y;
        double dz = (double)a.z - (double)b.z;
        double dw = (double)a.w - (double)b.w;
        ssq += dx * dx + dy * dy + dz * dz + dw * dw;

        const int row = rbase + 2 * i;
#pragma unroll
        for (int k = 0; k < 3; ++k) {
            if (active[k]) {
                float rok = (row >= by1[k] && row < by2[k]) ? 1.0f : 0.0f;
                float s = a.x * wm[k][0] + a.y * wm[k][1] + a.z * wm[k][2] + a.w * wm[k][3];
                bxs[k] = fmaf(rok, s, bxs[k]);
            }
        }
    }

    // Block reduction of 6 quantities.
    double b0 = (double)bxs[0], b1 = (double)bxs[1], b2 = (double)bxs[2];
    so = wave_reduce_d(so);
    sd = wave_reduce_d(sd);
    ssq = wave_reduce_d(ssq);
    b0 = wave_reduce_d(b0);
    b1 = wave_reduce_d(b1);
    b2 = wave_reduce_d(b2);

    __shared__ double sm[6][4];
    if (lane == 0) {
        sm[0][wid] = so; sm[1][wid] = sd; sm[2][wid] = ssq;
        sm[3][wid] = b0; sm[4][wid] = b1; sm[5][wid] = b2;
    }
    __syncthreads();
    if (t == 0) {
        ws[WS_SO + blk] = sm[0][0] + sm[0][1] + sm[0][2] + sm[0][3];
        ws[WS_SD + blk] = sm[1][0] + sm[1][1] + sm[1][2] + sm[1][3];
        ws[WS_SQ + blk] = sm[2][0] + sm[2][1] + sm[2][2] + sm[2][3];
#pragma unroll
        for (int k = 0; k < 3; ++k) {
            double bv = sm[3 + k][0] + sm[3 + k][1] + sm[3 + k][2] + sm[3 + k][3];
            ws[WS_BOX + (batch * 3 + k) * 32 + band] = bv;
        }
    }
    __syncthreads();

    // ---- last-block-done ticket ----
    __shared__ int s_last;
    if (t == 0) {
        __threadfence();  // release: make slot writes device-visible
        unsigned* ticket = (unsigned*)((char*)ws + WS_TICKET_BYTES);
        unsigned old = atomicAdd(ticket, 1u);
        s_last = (old == (unsigned)(N_BLOCKS - 1)) ? 1 : 0;
    }
    __syncthreads();
    if (!s_last) return;
    __threadfence();  // acquire: invalidate stale cached lines before reads

    // ---- finalize (256 threads) ----
    __shared__ double s_diff[32];  // per-batch (sum_o - sum_d)^2
    __shared__ double s_q[4];      // per-wave ssq partial
    __shared__ double s_m[4];      // per-wave min_count partial

    // count_loss: thread t sums slots [4t,4t+4); batch = t/8 (8 threads/batch)
    {
        double so4 = 0.0, sd4 = 0.0;
#pragma unroll
        for (int j = 0; j < 4; ++j) {
            so4 += ws[WS_SO + t * 4 + j];
            sd4 += ws[WS_SD + t * 4 + j];
        }
        for (int off = 4; off > 0; off >>= 1) {
            so4 += __shfl_down(so4, off, 8);
            sd4 += __shfl_down(sd4, off, 8);
        }
        if ((t & 7) == 0) {
            double d = so4 - sd4;
            s_diff[t >> 3] = d * d;
        }
    }

    // dmap ssq: thread t sums 4 slots, then full-wave reduce
    {
        double q = 0.0;
#pragma unroll
        for (int j = 0; j < 4; ++j) q += ws[WS_SQ + t * 4 + j];
        q = wave_reduce_d(q);
        if (lane == 0) s_q[wid] = q;
    }

    // min_count: 96 boxes x 32 bands; 8 threads/box x 4 slots, 3 passes of 32 boxes
    {
        double m = 0.0;
#pragma unroll
        for (int k = 0; k < 3; ++k) {
            int box = k * 32 + (t >> 3);
            double bs = 0.0;
#pragma unroll
            for (int j = 0; j < 4; ++j)
                bs += ws[WS_BOX + box * 32 + (t & 7) * 4 + j];
            for (int off = 4; off > 0; off >>= 1)
                bs += __shfl_down(bs, off, 8);
            if ((t & 7) == 0) {
                double r = 1.0 - bs;
                if (r > 0.0) m += r;
            }
        }
        m = wave_reduce_d(m);
        if (lane == 0) s_m[wid] = m;
    }

    __syncthreads();
    if (t == 0) {
        double cnt = 0.0;
        for (int i = 0; i < 32; ++i) cnt += s_diff[i];
        double q = s_q[0] + s_q[1] + s_q[2] + s_q[3];
        double m = s_m[0] + s_m[1] + s_m[2] + s_m[3];
        out[0] = (float)(q / (double)(*nobj));   // dmap_loss
        out[1] = (float)(cnt / (double)BATCH);   // count_loss
        out[2] = (float)m;                       // min_count
    }
}

extern "C" void kernel_launch(void* const* d_in, const int* in_sizes, int n_in,
                              void* d_out, int out_size, void* d_ws, size_t ws_size,
                              hipStream_t stream) {
    const float* output  = (const float*)d_in[0];
    const float* density = (const float*)d_in[1];
    const int*   bboxes  = (const int*)d_in[2];
    const int*   numobj  = (const int*)d_in[3];
    float* out = (float*)d_out;
    double* ws = (double*)d_ws;

    // Zero only the 4-byte ticket (ws is re-poisoned to 0xAA by the harness).
    hipMemsetAsync((char*)d_ws + WS_TICKET_BYTES, 0, sizeof(unsigned), stream);

    fused_all<<<N_BLOCKS, 256, 0, stream>>>(
        (const float4*)output, (const float4*)density, bboxes, ws, numobj, out);
}

// Round 5
// 108.420 us; speedup vs baseline: 1.2022x; 1.2022x over previous
//
#include <hip/hip_runtime.h>

// Problem constants: B=32, H=W=512
#define BATCH 32
#define HW 262144           // elements per image
#define HW4 65536           // float4 per image
#define W_IMG 512
#define N_BLOCKS 1024       // 32 batches * 32 bands (16 rows each)
#define N_BOX 96            // B * 3

// Workspace layout (doubles) — every slot written unconditionally by its block
// via relaxed AGENT-scope atomic stores (write-through, cross-XCD visible):
//  [0..1023]     per-block sum of output      (slot = batch*32 + band)
//  [1024..2047]  per-block sum of density
//  [2048..3071]  per-block sum of (o-d)^2
//  [3072..6143]  box partials: slot = box*32 + band  (96 boxes x 32 bands)
//  byte offset 6144*8: uint32 ticket (zeroed via hipMemsetAsync each launch)
#define WS_SO   0
#define WS_SD   1024
#define WS_SQ   2048
#define WS_BOX  3072
#define WS_TICKET_BYTES (6144 * 8)

__device__ __forceinline__ double wave_reduce_d(double v) {
    for (int off = 32; off > 0; off >>= 1)
        v += __shfl_down(v, off, 64);
    return v;
}

__device__ __forceinline__ void coh_store(double* p, double v) {
    __hip_atomic_store(p, v, __ATOMIC_RELAXED, __HIP_MEMORY_SCOPE_AGENT);
}
__device__ __forceinline__ double coh_load(const double* p) {
    return __hip_atomic_load(p, __ATOMIC_RELAXED, __HIP_MEMORY_SCOPE_AGENT);
}

// Single kernel: each block streams a 16-row band of one image computing
// sum(o), sum(d), sum((o-d)^2) and partials of its batch's 3 boxes from
// registers; the last block to finish reduces all partials and writes d_out.
// Coherence via sc1 write-through stores + sc1 loads — NO threadfence
// (device fences emit buffer_wbl2/buffer_inv = whole-L2 ops; round-4 showed
// 1024 of those cost ~58 us).
__global__ __launch_bounds__(256) void fused_all(const float4* __restrict__ o4,
                                                 const float4* __restrict__ d4,
                                                 const int* __restrict__ bb,
                                                 double* __restrict__ ws,
                                                 const int* __restrict__ nobj,
                                                 float* __restrict__ out) {
    const int blk = blockIdx.x;
    const int batch = blk >> 5;
    const int band = blk & 31;                 // rows [band*16, band*16+16)
    const size_t base = (size_t)blk * 2048;    // float4 index
    const int t = threadIdx.x;
    const int lane = t & 63;
    const int wid = t >> 6;
    const int col0 = (t & 127) * 4;            // constant per thread across iters
    const int rbase = band * 16 + (t >> 7);    // row at iter i = rbase + 2*i

    // Per-box precompute: column masks (constant per thread) + row range.
    float wm[3][4];
    int by1[3], by2[3];
    bool active[3];
#pragma unroll
    for (int k = 0; k < 3; ++k) {
        const int* p = bb + (batch * 3 + k) * 4;
        int x1 = min(max(p[0], 0), W_IMG);
        int y1 = min(max(p[1], 0), W_IMG);
        int x2 = min(max(p[2], 0), W_IMG);
        int y2 = min(max(p[3], 0), W_IMG);
        x2 = max(x2, x1);
        y2 = max(y2, y1);
        by1[k] = y1; by2[k] = y2;
#pragma unroll
        for (int j = 0; j < 4; ++j) {
            int c = col0 + j;
            wm[k][j] = (c >= x1 && c < x2) ? 1.0f : 0.0f;
        }
        active[k] = (y2 > band * 16) && (y1 < band * 16 + 16);  // block-uniform
    }

    double so = 0.0, sd = 0.0, ssq = 0.0;
    float bxs[3] = {0.0f, 0.0f, 0.0f};

#pragma unroll
    for (int i = 0; i < 8; ++i) {
        size_t idx = base + t + i * 256;
        float4 a = o4[idx];
        float4 b = d4[idx];
        so += (double)a.x + (double)a.y + (double)a.z + (double)a.w;
        sd += (double)b.x + (double)b.y + (double)b.z + (double)b.w;
        double dx = (double)a.x - (double)b.x;
        double dy = (double)a.y - (double)b.y;
        double dz = (double)a.z - (double)b.z;
        double dw = (double)a.w - (double)b.w;
        ssq += dx * dx + dy * dy + dz * dz + dw * dw;

        const int row = rbase + 2 * i;
#pragma unroll
        for (int k = 0; k < 3; ++k) {
            if (active[k]) {
                float rok = (row >= by1[k] && row < by2[k]) ? 1.0f : 0.0f;
                float s = a.x * wm[k][0] + a.y * wm[k][1] + a.z * wm[k][2] + a.w * wm[k][3];
                bxs[k] = fmaf(rok, s, bxs[k]);
            }
        }
    }

    // Block reduction of 6 quantities.
    double b0 = (double)bxs[0], b1 = (double)bxs[1], b2 = (double)bxs[2];
    so = wave_reduce_d(so);
    sd = wave_reduce_d(sd);
    ssq = wave_reduce_d(ssq);
    b0 = wave_reduce_d(b0);
    b1 = wave_reduce_d(b1);
    b2 = wave_reduce_d(b2);

    __shared__ double sm[6][4];
    if (lane == 0) {
        sm[0][wid] = so; sm[1][wid] = sd; sm[2][wid] = ssq;
        sm[3][wid] = b0; sm[4][wid] = b1; sm[5][wid] = b2;
    }
    __syncthreads();

    __shared__ int s_last;
    if (t == 0) {
        coh_store(&ws[WS_SO + blk], sm[0][0] + sm[0][1] + sm[0][2] + sm[0][3]);
        coh_store(&ws[WS_SD + blk], sm[1][0] + sm[1][1] + sm[1][2] + sm[1][3]);
        coh_store(&ws[WS_SQ + blk], sm[2][0] + sm[2][1] + sm[2][2] + sm[2][3]);
#pragma unroll
        for (int k = 0; k < 3; ++k) {
            double bv = sm[3 + k][0] + sm[3 + k][1] + sm[3 + k][2] + sm[3 + k][3];
            coh_store(&ws[WS_BOX + (batch * 3 + k) * 32 + band], bv);
        }
        // Drain the sc1 write-through stores, then bump the ticket (relaxed —
        // ordering is enforced by the explicit vmcnt wait, not a fence).
        __builtin_amdgcn_s_waitcnt(0);
        unsigned* ticket = (unsigned*)((char*)ws + WS_TICKET_BYTES);
        unsigned old = __hip_atomic_fetch_add(ticket, 1u, __ATOMIC_RELAXED,
                                              __HIP_MEMORY_SCOPE_AGENT);
        s_last = (old == (unsigned)(N_BLOCKS - 1)) ? 1 : 0;
    }
    __syncthreads();
    if (!s_last) return;

    // ---- finalize in the last block (256 threads); all slot reads are
    // sc1 coherent-point loads, immune to stale local L2 ----
    __shared__ double s_diff[32];  // per-batch (sum_o - sum_d)^2
    __shared__ double s_q[4];      // per-wave ssq partial
    __shared__ double s_m[4];      // per-wave min_count partial

    // count_loss: thread t sums slots [4t,4t+4); batch = t/8 (8 threads/batch)
    {
        double so4 = 0.0, sd4 = 0.0;
#pragma unroll
        for (int j = 0; j < 4; ++j) {
            so4 += coh_load(&ws[WS_SO + t * 4 + j]);
            sd4 += coh_load(&ws[WS_SD + t * 4 + j]);
        }
        for (int off = 4; off > 0; off >>= 1) {
            so4 += __shfl_down(so4, off, 8);
            sd4 += __shfl_down(sd4, off, 8);
        }
        if ((t & 7) == 0) {
            double d = so4 - sd4;
            s_diff[t >> 3] = d * d;
        }
    }

    // dmap ssq: thread t sums 4 slots, then full-wave reduce
    {
        double q = 0.0;
#pragma unroll
        for (int j = 0; j < 4; ++j) q += coh_load(&ws[WS_SQ + t * 4 + j]);
        q = wave_reduce_d(q);
        if (lane == 0) s_q[wid] = q;
    }

    // min_count: 96 boxes x 32 bands; 8 threads/box x 4 slots, 3 passes of 32 boxes
    {
        double m = 0.0;
#pragma unroll
        for (int k = 0; k < 3; ++k) {
            int box = k * 32 + (t >> 3);
            double bs = 0.0;
#pragma unroll
            for (int j = 0; j < 4; ++j)
                bs += coh_load(&ws[WS_BOX + box * 32 + (t & 7) * 4 + j]);
            for (int off = 4; off > 0; off >>= 1)
                bs += __shfl_down(bs, off, 8);
            if ((t & 7) == 0) {
                double r = 1.0 - bs;
                if (r > 0.0) m += r;
            }
        }
        m = wave_reduce_d(m);
        if (lane == 0) s_m[wid] = m;
    }

    __syncthreads();
    if (t == 0) {
        double cnt = 0.0;
        for (int i = 0; i < 32; ++i) cnt += s_diff[i];
        double q = s_q[0] + s_q[1] + s_q[2] + s_q[3];
        double m = s_m[0] + s_m[1] + s_m[2] + s_m[3];
        out[0] = (float)(q / (double)(*nobj));   // dmap_loss
        out[1] = (float)(cnt / (double)BATCH);   // count_loss
        out[2] = (float)m;                       // min_count
    }
}

extern "C" void kernel_launch(void* const* d_in, const int* in_sizes, int n_in,
                              void* d_out, int out_size, void* d_ws, size_t ws_size,
                              hipStream_t stream) {
    const float* output  = (const float*)d_in[0];
    const float* density = (const float*)d_in[1];
    const int*   bboxes  = (const int*)d_in[2];
    const int*   numobj  = (const int*)d_in[3];
    float* out = (float*)d_out;
    double* ws = (double*)d_ws;

    // Zero only the 4-byte ticket (ws is re-poisoned to 0xAA by the harness).
    hipMemsetAsync((char*)d_ws + WS_TICKET_BYTES, 0, sizeof(unsigned), stream);

    fused_all<<<N_BLOCKS, 256, 0, stream>>>(
        (const float4*)output, (const float4*)density, bboxes, ws, numobj, out);
}

// Round 6
// 99.891 us; speedup vs baseline: 1.3048x; 1.0854x over previous
//
#include <hip/hip_runtime.h>

// Problem constants: B=32, H=W=512
#define BATCH 32
#define HW 262144           // elements per image
#define HW4 65536           // float4 per image
#define W_IMG 512
#define N_BLOCKS 1024       // 32 batches * 32 bands (16 rows each)
#define N_BOX 96            // B * 3

// Workspace layout (doubles) — every slot written unconditionally, no init:
//  [0..1023]     per-block sum of output      (slot = batch*32 + band)
//  [1024..2047]  per-block sum of density
//  [2048..3071]  per-block sum of (o-d)^2
//  [3072..6143]  box partials: slot = box*32 + band  (96 boxes x 32 bands)
#define WS_SO   0
#define WS_SD   1024
#define WS_SQ   2048
#define WS_BOX  3072

__device__ __forceinline__ double wave_reduce_d(double v) {
    for (int off = 32; off > 0; off >>= 1)
        v += __shfl_down(v, off, 64);
    return v;
}

// Kernel 1: each block streams a 16-row band of one image, computing
// sum(o), sum(d), sum((o-d)^2), and partials of the 3 boxes of its batch
// from the data already in registers. Plain stores — the kernel boundary
// is the coherence point (rounds 4/5 proved fences/tickets cost more).
__global__ __launch_bounds__(256) void fused_partials(const float4* __restrict__ o4,
                                                      const float4* __restrict__ d4,
                                                      const int* __restrict__ bb,
                                                      double* __restrict__ ws) {
    const int blk = blockIdx.x;
    const int batch = blk >> 5;
    const int band = blk & 31;                 // rows [band*16, band*16+16)
    const size_t base = (size_t)blk * 2048;    // float4 index
    const int t = threadIdx.x;
    const int col0 = (t & 127) * 4;            // constant per thread across iters
    const int rbase = band * 16 + (t >> 7);    // row at iter i = rbase + 2*i

    // Per-box precompute: column masks (constant per thread) + row range.
    float wm[3][4];
    int by1[3], by2[3];
    bool active[3];
#pragma unroll
    for (int k = 0; k < 3; ++k) {
        const int* p = bb + (batch * 3 + k) * 4;
        int x1 = min(max(p[0], 0), W_IMG);
        int y1 = min(max(p[1], 0), W_IMG);
        int x2 = min(max(p[2], 0), W_IMG);
        int y2 = min(max(p[3], 0), W_IMG);
        x2 = max(x2, x1);
        y2 = max(y2, y1);
        by1[k] = y1; by2[k] = y2;
#pragma unroll
        for (int j = 0; j < 4; ++j) {
            int c = col0 + j;
            wm[k][j] = (c >= x1 && c < x2) ? 1.0f : 0.0f;
        }
        active[k] = (y2 > band * 16) && (y1 < band * 16 + 16);  // block-uniform
    }

    double so = 0.0, sd = 0.0, ssq = 0.0;
    float bxs[3] = {0.0f, 0.0f, 0.0f};

#pragma unroll
    for (int i = 0; i < 8; ++i) {
        size_t idx = base + t + i * 256;
        float4 a = o4[idx];
        float4 b = d4[idx];
        so += (double)a.x + (double)a.y + (double)a.z + (double)a.w;
        sd += (double)b.x + (double)b.y + (double)b.z + (double)b.w;
        double dx = (double)a.x - (double)b.x;
        double dy = (double)a.y - (double)b.y;
        double dz = (double)a.z - (double)b.z;
        double dw = (double)a.w - (double)b.w;
        ssq += dx * dx + dy * dy + dz * dz + dw * dw;

        const int row = rbase + 2 * i;
#pragma unroll
        for (int k = 0; k < 3; ++k) {
            if (active[k]) {
                float rok = (row >= by1[k] && row < by2[k]) ? 1.0f : 0.0f;
                float s = a.x * wm[k][0] + a.y * wm[k][1] + a.z * wm[k][2] + a.w * wm[k][3];
                bxs[k] = fmaf(rok, s, bxs[k]);
            }
        }
    }

    // Block reduction of 6 quantities.
    const int lane = t & 63;
    const int wid = t >> 6;
    double b0 = (double)bxs[0], b1 = (double)bxs[1], b2 = (double)bxs[2];
    so = wave_reduce_d(so);
    sd = wave_reduce_d(sd);
    ssq = wave_reduce_d(ssq);
    b0 = wave_reduce_d(b0);
    b1 = wave_reduce_d(b1);
    b2 = wave_reduce_d(b2);

    __shared__ double sm[6][4];
    if (lane == 0) {
        sm[0][wid] = so; sm[1][wid] = sd; sm[2][wid] = ssq;
        sm[3][wid] = b0; sm[4][wid] = b1; sm[5][wid] = b2;
    }
    __syncthreads();
    if (t == 0) {
        ws[WS_SO + blk] = sm[0][0] + sm[0][1] + sm[0][2] + sm[0][3];
        ws[WS_SD + blk] = sm[1][0] + sm[1][1] + sm[1][2] + sm[1][3];
        ws[WS_SQ + blk] = sm[2][0] + sm[2][1] + sm[2][2] + sm[2][3];
#pragma unroll
        for (int k = 0; k < 3; ++k) {
            double bv = sm[3 + k][0] + sm[3 + k][1] + sm[3 + k][2] + sm[3 + k][3];
            ws[WS_BOX + (batch * 3 + k) * 32 + band] = bv;
        }
    }
}

// Kernel 2: finalize. 1 block, 256 threads.
__global__ __launch_bounds__(256) void finalize(const double* __restrict__ ws,
                                                const int* __restrict__ nobj,
                                                float* __restrict__ out) {
    const int t = threadIdx.x;
    const int lane = t & 63;
    const int wid = t >> 6;

    __shared__ double s_diff[32];  // per-batch (sum_o - sum_d)^2
    __shared__ double s_q[4];      // per-wave ssq partial
    __shared__ double s_m[4];      // per-wave min_count partial

    // count_loss: thread t sums slots [4t,4t+4); batch = t/8 (8 threads/batch)
    {
        double so4 = 0.0, sd4 = 0.0;
#pragma unroll
        for (int j = 0; j < 4; ++j) {
            so4 += ws[WS_SO + t * 4 + j];
            sd4 += ws[WS_SD + t * 4 + j];
        }
        for (int off = 4; off > 0; off >>= 1) {
            so4 += __shfl_down(so4, off, 8);
            sd4 += __shfl_down(sd4, off, 8);
        }
        if ((t & 7) == 0) {
            double d = so4 - sd4;
            s_diff[t >> 3] = d * d;
        }
    }

    // dmap ssq: thread t sums 4 slots, then full-wave reduce
    {
        double q = 0.0;
#pragma unroll
        for (int j = 0; j < 4; ++j) q += ws[WS_SQ + t * 4 + j];
        q = wave_reduce_d(q);
        if (lane == 0) s_q[wid] = q;
    }

    // min_count: 96 boxes x 32 bands; 8 threads/box x 4 slots, 3 passes of 32 boxes
    {
        double m = 0.0;
#pragma unroll
        for (int k = 0; k < 3; ++k) {
            int box = k * 32 + (t >> 3);
            double bs = 0.0;
#pragma unroll
            for (int j = 0; j < 4; ++j)
                bs += ws[WS_BOX + box * 32 + (t & 7) * 4 + j];
            for (int off = 4; off > 0; off >>= 1)
                bs += __shfl_down(bs, off, 8);
            if ((t & 7) == 0) {
                double r = 1.0 - bs;
                if (r > 0.0) m += r;
            }
        }
        m = wave_reduce_d(m);
        if (lane == 0) s_m[wid] = m;
    }

    __syncthreads();
    if (t == 0) {
        double cnt = 0.0;
        for (int i = 0; i < 32; ++i) cnt += s_diff[i];
        double q = s_q[0] + s_q[1] + s_q[2] + s_q[3];
        double m = s_m[0] + s_m[1] + s_m[2] + s_m[3];
        out[0] = (float)(q / (double)(*nobj));   // dmap_loss
        out[1] = (float)(cnt / (double)BATCH);   // count_loss
        out[2] = (float)m;                       // min_count
    }
}

extern "C" void kernel_launch(void* const* d_in, const int* in_sizes, int n_in,
                              void* d_out, int out_size, void* d_ws, size_t ws_size,
                              hipStream_t stream) {
    const float* output  = (const float*)d_in[0];
    const float* density = (const float*)d_in[1];
    const int*   bboxes  = (const int*)d_in[2];
    const int*   numobj  = (const int*)d_in[3];
    float* out = (float*)d_out;
    double* ws = (double*)d_ws;

    fused_partials<<<N_BLOCKS, 256, 0, stream>>>(
        (const float4*)output, (const float4*)density, bboxes, ws);

    finalize<<<1, 256, 0, stream>>>(ws, numobj, out);
}